// Round 9
// baseline (157.709 us; speedup 1.0000x reference)
//
#include <hip/hip_runtime.h>
#include <hip/hip_bf16.h>
#include <cstdint>

typedef unsigned short u16;
typedef __bf16 bf16x8 __attribute__((ext_vector_type(8)));
typedef float f32x4 __attribute__((ext_vector_type(4)));

#define S_LEN 2048
#define NH 16
#define DK 64
#define DM 1024

__device__ __forceinline__ u16 f2bf(float f) {
  union { float f; uint32_t u; } c; c.f = f;
  uint32_t u = c.u;
  u += 0x7fffu + ((u >> 16) & 1u);   // RNE
  return (u16)(u >> 16);
}

__device__ __forceinline__ void gl_lds16(const void* gsrc, void* ldst) {
  __builtin_amdgcn_global_load_lds(
      (const __attribute__((address_space(1))) unsigned int*)gsrc,
      (__attribute__((address_space(3))) unsigned int*)ldst,
      16, 0, 0);
}

#define MFMA16(a, b, c) __builtin_amdgcn_mfma_f32_16x16x32_bf16((a), (b), (c), 0, 0, 0)
#define VMW(N) asm volatile("s_waitcnt vmcnt(" #N ")" ::: "memory")
#define BARM() asm volatile("s_barrier" ::: "memory")

// ---------------- fp32 -> bf16 conversion (x + 4 weights) ----------------
__global__ __launch_bounds__(256) void convert_all(
    const float* x, const float* wq, const float* wk, const float* wv, const float* wo,
    u16* xb, u16* wqb, u16* wkb, u16* wvb, u16* wob)
{
  size_t i = ((size_t)blockIdx.x * 256 + threadIdx.x) * 4;
  const float* src; u16* dst; size_t off;
  if (i < 4194304u)      { src = x;  dst = xb;  off = i; }
  else if (i < 5242880u) { src = wq; dst = wqb; off = i - 4194304u; }
  else if (i < 6291456u) { src = wk; dst = wkb; off = i - 5242880u; }
  else if (i < 7340032u) { src = wv; dst = wvb; off = i - 6291456u; }
  else                   { src = wo; dst = wob; off = i - 7340032u; }
  float4 v = *(const float4*)(src + off);
  ushort4 o;
  o.x = f2bf(v.x); o.y = f2bf(v.y); o.z = f2bf(v.z); o.w = f2bf(v.w);
  *(ushort4*)(dst + off) = o;
}

// ---------------- RoPE cos/sin table ----------------
__global__ __launch_bounds__(256) void rope_tab_k(float2* tab) {
  int i = blockIdx.x * 256 + threadIdx.x;   // 65536 entries
  int pos = i >> 5, f = i & 31;
  float inv = powf(10000.0f, -(float)f / 32.0f);
  float ang = (float)pos * inv;
  tab[i] = make_float2(cosf(ang), sinf(ang));
}

// ---------------- per-(b, kv-tile-of-64) all-valid flags ----------------
__global__ __launch_bounds__(64) void mask_flags(const int* amask, int* mflag) {
  const int f = blockIdx.x;               // 0..63: b = f>>5, tile = f&31
  const int b = f >> 5, t = f & 31;
  int v = amask[b * S_LEN + t * 64 + threadIdx.x];
  int all = (int)__all(v != 0);
  if (threadIdx.x == 0) mflag[f] = all;
}

// ================= 256x256 8-phase counted-vmcnt GEMM core =================
// 512 thr, 8 waves (2M x 4N), per-wave 128x64 output. K=1024, BK=64 (16 steps).
// LDS 128 KB (A,B each 2buf x 256x64 bf16). Per K-step: 4 phases, each
// {ds_read subtile | stage 1 half-tile (2 gl_lds) -> barrier -> 16 MFMA -> barrier}.
// Stage schedule: A(t+1) halves at p0/p1 (into nx); B(t+2) halves at p2/p3
// (into cur -- overwrites B chunks whose last ds_read was p1, >=1 barrier ago).
// Single VMW(4) per K-step at p3 (before its end barrier): drains everything
// except the 2 newest halves; all of tile t+1 (A: t p0/p1, B: t-1 p2/p3) is
// complete before t+1 p0's reads. Never drains to 0 until the tail (t=14).
__device__ __forceinline__ void gemm256_8ph(
    const u16* A, const u16* Bp, int m0, int n0,
    u16 (&ldsA)[2][256 * 64], u16 (&ldsB)[2][256 * 64], f32x4 (&acc)[8][4])
{
  const int tid = threadIdx.x;
  const int w8 = tid >> 6, lane = tid & 63;
  const int wm = w8 >> 2, wn = w8 & 3;
  const int l15 = lane & 15, g = lane >> 4;
  const int swb = ((lane & 7) * 16) ^ (((lane >> 3) & 7) << 4);

  bf16x8 aF[4][2];       // current qm-half A frags (reloaded at p2)
  bf16x8 bF[2][2][2];    // both qn B frags (live p0..p3)

  auto stA = [&](int buf, int kt, int c0) {
#pragma unroll
    for (int c = 0; c < 2; ++c) {
      const int rb = (c0 + c) * 64 + w8 * 8;
      const int row = rb + (lane >> 3);
      gl_lds16((const char*)(A + (size_t)(m0 + row) * DM + kt * 64) + swb,
               (char*)&ldsA[buf][0] + rb * 128);
    }
  };
  auto stB = [&](int buf, int kt, int c0) {
#pragma unroll
    for (int c = 0; c < 2; ++c) {
      const int rb = (c0 + c) * 64 + w8 * 8;
      const int row = rb + (lane >> 3);
      gl_lds16((const char*)(Bp + (size_t)(n0 + row) * DM + kt * 64) + swb,
               (char*)&ldsB[buf][0] + rb * 128);
    }
  };
  auto ldA = [&](int cur, int qm) {
#pragma unroll
    for (int f = 0; f < 4; ++f) {
      const int row = qm * 128 + wm * 64 + f * 16 + l15;
#pragma unroll
      for (int kk = 0; kk < 2; ++kk)
        aF[f][kk] = *(const bf16x8*)((const char*)&ldsA[cur][0] + row * 128 +
                                     ((kk * 64 + g * 16) ^ ((row & 7) << 4)));
    }
  };
  auto ldB = [&](int cur, int qn) {
#pragma unroll
    for (int f2 = 0; f2 < 2; ++f2) {
      const int row = wn * 64 + qn * 32 + f2 * 16 + l15;
#pragma unroll
      for (int kk = 0; kk < 2; ++kk)
        bF[qn][f2][kk] = *(const bf16x8*)((const char*)&ldsB[cur][0] + row * 128 +
                                          ((kk * 64 + g * 16) ^ ((row & 7) << 4)));
    }
  };
  auto quad = [&](int qm, int qn) {
    __builtin_amdgcn_s_setprio(1);
#pragma unroll
    for (int f = 0; f < 4; ++f)
#pragma unroll
      for (int f2 = 0; f2 < 2; ++f2)
#pragma unroll
        for (int kk = 0; kk < 2; ++kk)
          acc[qm * 4 + f][qn * 2 + f2] =
              MFMA16(aF[f][kk], bF[qn][f2][kk], acc[qm * 4 + f][qn * 2 + f2]);
    __builtin_amdgcn_s_setprio(0);
  };

  // prologue: B(0),A(0) -> buf0 ; B(1) -> buf1  (12 loads; VMW(4) keeps B(1) in flight)
  stB(0, 0, 0); stB(0, 0, 2);
  stA(0, 0, 0); stA(0, 0, 2);
  stB(1, 1, 0); stB(1, 1, 2);
  VMW(4);
  BARM();

  for (int t = 0; t < 16; ++t) {
    const int cur = t & 1, nx = cur ^ 1;
    // p0: quad(0,0) -- reads A-half0 + B-qn0 (12 ds_reads)
    ldA(cur, 0); ldB(cur, 0);
    if (t < 15) stA(nx, t + 1, 0);
    BARM();
    quad(0, 0);
    BARM();
    // p1: quad(0,1) -- reads B-qn1 (4 ds_reads; A0 cached)
    ldB(cur, 1);
    if (t < 15) stA(nx, t + 1, 2);
    BARM();
    quad(0, 1);
    BARM();
    // p2: quad(1,0) -- reads A-half1 (8 ds_reads; B cached). B-chunk01 of cur
    // re-staged here for t+2 (its last ds_read was p1, one barrier ago).
    ldA(cur, 1);
    if (t < 14) stB(cur, t + 2, 0);
    BARM();
    quad(1, 0);
    BARM();
    // p3: quad(1,1) -- regs only; stage B-chunk23(t+2); the one drain point.
    if (t < 14) stB(cur, t + 2, 2);
    BARM();
    quad(1, 1);
    if (t < 14) { VMW(4); } else if (t == 14) { VMW(0); }
    BARM();
  }
}

// ================= fused QKV projection (8-phase core) + RoPE/V-transpose =================
// Grid 192: mt = bid&15 (M=4096/256), nt = bid>>4 (0..11) over N=3072 (Q|K|V).
__global__ __launch_bounds__(512, 2) void gemm_qkv256(
    const u16* xb, const u16* wqb, const u16* wkb, const u16* wvb,
    const float2* tab, u16* Qr, u16* Kr, u16* Vt)
{
  __shared__ __align__(16) u16 ldsA[2][256 * 64];
  __shared__ __align__(16) u16 ldsB[2][256 * 64];

  const int bid = blockIdx.x;
  const int mt = bid & 15, nt = bid >> 4;
  const int m0 = mt * 256;
  const int z = nt >> 2;                      // 0=Q 1=K 2=V
  const int n0z = (nt & 3) * 256;
  const u16* Wz = (z == 0) ? wqb : ((z == 1) ? wkb : wvb);

  f32x4 acc[8][4] = {};
  gemm256_8ph(xb, Wz, m0, n0z, ldsA, ldsB, acc);

  const int tid = threadIdx.x;
  const int w8 = tid >> 6, lane = tid & 63;
  const int wm = w8 >> 2, wn = w8 & 3;
  const int l15 = lane & 15, g = lane >> 4;
  u16* dst = (z == 0) ? Qr : Kr;
#pragma unroll
  for (int fm = 0; fm < 8; ++fm) {
    const int row0 = m0 + (fm >> 2) * 128 + wm * 64 + (fm & 3) * 16 + g * 4;
#pragma unroll
    for (int fn = 0; fn < 4; ++fn) {
      const int col = n0z + wn * 64 + (fn >> 1) * 32 + (fn & 1) * 16 + l15;
      const int h = col >> 6, d = col & 63;
#pragma unroll
      for (int r = 0; r < 4; ++r) {
        const int m = row0 + r;
        const int b = m >> 11, s = m & 2047;
        float vv = acc[fm][fn][r];
        if (z < 2) {
          float p = __shfl_xor(vv, 1);
          float2 cs = tab[s * 32 + (d >> 1)];
          float o = vv * cs.x + ((d & 1) ? p : -p) * cs.y;
          if (z == 0) o *= 0.125f;            // fold 1/sqrt(DK) into Q
          dst[((size_t)(b * NH + h) * S_LEN + s) * DK + d] = f2bf(o);
        } else {
          Vt[((size_t)(b * NH + h) * DK + d) * S_LEN + s] = f2bf(vv);
        }
      }
    }
  }
}

// ---------------- output GEMM: counted-vmcnt double-buffered 128x128 (unchanged) ----------------
__device__ __forceinline__ void xcd_map(int bid, int& m0, int& n0) {
  const int xcd = bid & 7, v = bid >> 3;
  m0 = (xcd * 4 + (v >> 3)) * 128;
  n0 = (v & 7) * 128;
}

__global__ __launch_bounds__(256) void gemm_out(const u16* ctx, const u16* wob, float* out) {
  __shared__ __align__(16) u16 ldsA[2][128 * 64];
  __shared__ __align__(16) u16 ldsB[2][128 * 64];
  int m0, n0;
  xcd_map(blockIdx.x, m0, n0);

  const int tid = threadIdx.x;
  const int w = tid >> 6, lane = tid & 63;
  const int l15 = lane & 15, g = lane >> 4;
  const int wm = (w >> 1) * 64, wn = (w & 1) * 64;
  const int lrow = lane >> 3;
  const int scolb = ((lane & 7) * 16) ^ (lrow << 4);
  f32x4 acc[4][4] = {};

  auto stage = [&](int buf, int kt) {
#pragma unroll
    for (int c = 0; c < 4; ++c) {
      const int rb = w * 32 + c * 8;
      const int row = rb + lrow;
      gl_lds16((const char*)(ctx + (size_t)(m0 + row) * DM + kt) + scolb,
               (char*)&ldsA[buf][0] + rb * 128);
      gl_lds16((const char*)(wob + (size_t)(n0 + row) * DM + kt) + scolb,
               (char*)&ldsB[buf][0] + rb * 128);
    }
  };

  stage(0, 0);
  int cur = 0;
  for (int kt = 0; kt < DM; kt += 64) {
    if (kt + 64 < DM) { stage(cur ^ 1, kt + 64); VMW(8); } else { VMW(0); }
    BARM();
#pragma unroll
    for (int ks = 0; ks < 2; ++ks) {
      bf16x8 af[4], bfr[4];
#pragma unroll
      for (int i = 0; i < 4; ++i) {
        const int ar = wm + i * 16 + l15;
        af[i] = *(const bf16x8*)((const char*)&ldsA[cur][0] + ar * 128 +
                                 ((ks * 64 + g * 16) ^ ((ar & 7) << 4)));
        const int br = wn + i * 16 + l15;
        bfr[i] = *(const bf16x8*)((const char*)&ldsB[cur][0] + br * 128 +
                                  ((ks * 64 + g * 16) ^ ((br & 7) << 4)));
      }
      __builtin_amdgcn_s_setprio(1);
#pragma unroll
      for (int i = 0; i < 4; ++i)
#pragma unroll
        for (int j = 0; j < 4; ++j)
          acc[i][j] = MFMA16(af[i], bfr[j], acc[i][j]);
      __builtin_amdgcn_s_setprio(0);
    }
    BARM();
    cur ^= 1;
  }

#pragma unroll
  for (int i = 0; i < 4; ++i)
#pragma unroll
    for (int j = 0; j < 4; ++j)
#pragma unroll
      for (int r = 0; r < 4; ++r)
        out[(size_t)(m0 + wm + i * 16 + g * 4 + r) * DM + n0 + wn + j * 16 + l15] = acc[i][j][r];
}

// ---------------- causal flash attention (8 waves x 16 q-rows, CU-balanced bands) ----------------
__global__ __launch_bounds__(512, 4) void attn11(
    const u16* Qr, const u16* Kr, const u16* Vt, const int* amask, const int* mflag,
    u16* ctx)
{
  __shared__ __align__(16) u16 ldsK[2][64 * 64];
  __shared__ __align__(16) u16 ldsV[2][64 * 64];
  __shared__ __align__(16) __bf16 plds[8][16 * 72];

  const int bh = blockIdx.x;
  const int by = blockIdx.y;
  const int band = (by < 8) ? (15 - by) : (by - 8);   // CU-pairs sum to 15
  const int b = bh >> 4, h = bh & 15;
  const int tid = threadIdx.x, w8 = tid >> 6, lane = tid & 63;
  const int l15 = lane & 15, g = lane >> 4;
  const int r8 = lane >> 3;
  const int sw = ((lane & 7) * 16) ^ (r8 << 4);

  const int chunk = band * 4 + (w8 >> 1);          // 32-row chunk, 0..63
  const int q0 = chunk * 32 + (w8 & 1) * 16;
  const int myNt = (chunk >> 1) + 1;
  const int dTile = chunk >> 1;
  const int ntB = band * 2 + 2;

  const u16* Kb0 = Kr + (size_t)bh * S_LEN * DK;
  const u16* Vb0 = Vt + (size_t)bh * DK * S_LEN;
  const u16* Qb  = Qr + (size_t)bh * S_LEN * DK;

  bf16x8 qa0 = *(const bf16x8*)(Qb + (size_t)(q0 + l15) * DK + g * 8);
  bf16x8 qa1 = *(const bf16x8*)(Qb + (size_t)(q0 + l15) * DK + 32 + g * 8);

  union { u16 u[8]; bf16x8 v; } one_u;
#pragma unroll
  for (int i = 0; i < 8; ++i) one_u.u[i] = 0x3F80;
  const bf16x8 ones = one_u.v;

  float m[4];
  f32x4 lacc = {0.f, 0.f, 0.f, 0.f};
  f32x4 o[4];
#pragma unroll
  for (int r = 0; r < 4; ++r) m[r] = -3e38f;
#pragma unroll
  for (int dt = 0; dt < 4; ++dt) o[dt] = (f32x4){0.f, 0.f, 0.f, 0.f};

  auto stage = [&](int buf, int t) {
    const size_t kv0 = (size_t)t * 64;
    const int row = w8 * 8 + r8;
    gl_lds16((const char*)(Kb0 + (kv0 + row) * DK) + sw,
             (char*)&ldsK[buf][0] + (w8 * 8) * 128);
    gl_lds16((const char*)(Vb0 + (size_t)row * S_LEN + kv0) + sw,
             (char*)&ldsV[buf][0] + (w8 * 8) * 128);
  };

  stage(0, 0);
  int cur = 0;

  for (int t = 0; t < ntB; ++t) {
    if (t + 1 < ntB) { stage(cur ^ 1, t + 1); VMW(2); } else { VMW(0); }
    BARM();
    if (t < myNt) {
      const int kv0 = t * 64;
      const bool allok = mflag[(b << 5) + t] != 0;

      bf16x8 kb[4][2];
#pragma unroll
      for (int nt = 0; nt < 4; ++nt) {
        const int row = nt * 16 + l15;
#pragma unroll
        for (int ks = 0; ks < 2; ++ks)
          kb[nt][ks] = *(const bf16x8*)((const char*)&ldsK[cur][0] + row * 128 +
                                        ((ks * 64 + g * 16) ^ ((row & 7) << 4)));
      }
      f32x4 s[4];
#pragma unroll
      for (int nt = 0; nt < 4; ++nt) s[nt] = (f32x4){0.f, 0.f, 0.f, 0.f};
      __builtin_amdgcn_s_setprio(1);
#pragma unroll
      for (int nt = 0; nt < 4; ++nt) {
        s[nt] = MFMA16(qa0, kb[nt][0], s[nt]);
        s[nt] = MFMA16(qa1, kb[nt][1], s[nt]);
      }
      __builtin_amdgcn_s_setprio(0);

      if (!allok) {
#pragma unroll
        for (int nt = 0; nt < 4; ++nt) {
          const int pmv = amask[b * S_LEN + kv0 + nt * 16 + l15];
#pragma unroll
          for (int r = 0; r < 4; ++r)
            if (!pmv) s[nt][r] = -1e9f;
        }
      }
      if (t == dTile) {
#pragma unroll
        for (int nt = 0; nt < 4; ++nt) {
          const int kvc = kv0 + nt * 16 + l15;
#pragma unroll
          for (int r = 0; r < 4; ++r)
            s[nt][r] = (kvc <= q0 + g * 4 + r) ? s[nt][r] : -1e9f;
        }
      }

      float tmax[4];
      bool need = false;
#pragma unroll
      for (int r = 0; r < 4; ++r) {
        float t0 = fmaxf(fmaxf(s[0][r], s[1][r]), fmaxf(s[2][r], s[3][r]));
        t0 = fmaxf(t0, __shfl_xor(t0, 1));
        t0 = fmaxf(t0, __shfl_xor(t0, 2));
        t0 = fmaxf(t0, __shfl_xor(t0, 4));
        t0 = fmaxf(t0, __shfl_xor(t0, 8));
        tmax[r] = t0;
        need = need || (t0 > m[r] + 8.f);
      }
      if (__any((int)need)) {                // T13: rescale only on growth
#pragma unroll
        for (int r = 0; r < 4; ++r) {
          const float mnew = fmaxf(m[r], tmax[r]);
          const float alpha = __expf(m[r] - mnew);
          m[r] = mnew;
          lacc[r] *= alpha;
#pragma unroll
          for (int dt = 0; dt < 4; ++dt) o[dt][r] *= alpha;
        }
      }
      __bf16* pw = &plds[w8][0];
#pragma unroll
      for (int r = 0; r < 4; ++r) {
#pragma unroll
        for (int nt = 0; nt < 4; ++nt)
          pw[(g * 4 + r) * 72 + nt * 16 + l15] = (__bf16)__expf(s[nt][r] - m[r]);
      }
      bf16x8 pa0 = *(const bf16x8*)(pw + l15 * 72 + g * 8);
      bf16x8 pa1 = *(const bf16x8*)(pw + l15 * 72 + 32 + g * 8);
      bf16x8 vb[4][2];
#pragma unroll
      for (int dt = 0; dt < 4; ++dt) {
        const int row = dt * 16 + l15;
#pragma unroll
        for (int ks = 0; ks < 2; ++ks)
          vb[dt][ks] = *(const bf16x8*)((const char*)&ldsV[cur][0] + row * 128 +
                                        ((ks * 64 + g * 16) ^ ((row & 7) << 4)));
      }
      __builtin_amdgcn_s_setprio(1);
      lacc = MFMA16(pa0, ones, lacc);
      lacc = MFMA16(pa1, ones, lacc);
#pragma unroll
      for (int dt = 0; dt < 4; ++dt) {
        o[dt] = MFMA16(pa0, vb[dt][0], o[dt]);
        o[dt] = MFMA16(pa1, vb[dt][1], o[dt]);
      }
      __builtin_amdgcn_s_setprio(0);
    }
    BARM();
    cur ^= 1;
  }

#pragma unroll
  for (int dt = 0; dt < 4; ++dt)
#pragma unroll
    for (int r = 0; r < 4; ++r) {
      const int q = q0 + g * 4 + r;
      ctx[((size_t)(b * S_LEN + q)) * DM + h * DK + dt * 16 + l15] =
          f2bf(o[dt][r] / lacc[r]);
    }
}

extern "C" void kernel_launch(void* const* d_in, const int* in_sizes, int n_in,
                              void* d_out, int out_size, void* d_ws, size_t ws_size,
                              hipStream_t stream) {
  const float* x   = (const float*)d_in[0];
  const int* amask = (const int*)d_in[1];
  const float* wq  = (const float*)d_in[2];
  const float* wk  = (const float*)d_in[3];
  const float* wv  = (const float*)d_in[4];
  const float* wo  = (const float*)d_in[5];
  float* out = (float*)d_out;

  char* ws = (char*)d_ws;
  u16* xb    = (u16*)(ws);                      // 8 MB
  u16* wqb   = (u16*)(ws + ( 8u << 20));        // 2 MB
  u16* wkb   = (u16*)(ws + (10u << 20));
  u16* wvb   = (u16*)(ws + (12u << 20));
  u16* wob   = (u16*)(ws + (14u << 20));
  float2* tab = (float2*)(ws + (16u << 20));    // 512 KB
  int* mflag = (int*)(ws + (16u << 20) + (768u << 10));   // 256 B
  u16* Qr    = (u16*)(ws + (17u << 20));        // 8 MB  [B,H,S,D]
  u16* Kr    = (u16*)(ws + (25u << 20));        // 8 MB  [B,H,S,D]
  u16* Vt    = (u16*)(ws + (33u << 20));        // 8 MB  [B,H,D,S]
  u16* ctx   = (u16*)(ws + (41u << 20));        // 8 MB  [B,S,H*D]

  hipLaunchKernelGGL(convert_all, dim3(8192), dim3(256), 0, stream,
                     x, wq, wk, wv, wo, xb, wqb, wkb, wvb, wob);
  hipLaunchKernelGGL(rope_tab_k, dim3(256), dim3(256), 0, stream, tab);
  hipLaunchKernelGGL(mask_flags, dim3(64), dim3(64), 0, stream, amask, mflag);
  hipLaunchKernelGGL(gemm_qkv256, dim3(192), dim3(512), 0, stream,
                     xb, wqb, wkb, wvb, tab, Qr, Kr, Vt);
  hipLaunchKernelGGL(attn11, dim3(32, 16), dim3(512), 0, stream,
                     Qr, Kr, Vt, amask, mflag, ctx);
  hipLaunchKernelGGL(gemm_out, dim3(256), dim3(256), 0, stream, ctx, wob, out);
}

// Round 10
// 153.466 us; speedup vs baseline: 1.0276x; 1.0276x over previous
//
#include <hip/hip_runtime.h>
#include <hip/hip_bf16.h>
#include <cstdint>

typedef unsigned short u16;
typedef __bf16 bf16x8 __attribute__((ext_vector_type(8)));
typedef float f32x4 __attribute__((ext_vector_type(4)));

#define S_LEN 2048
#define NH 16
#define DK 64
#define DM 1024

__device__ __forceinline__ u16 f2bf(float f) {
  union { float f; uint32_t u; } c; c.f = f;
  uint32_t u = c.u;
  u += 0x7fffu + ((u >> 16) & 1u);   // RNE
  return (u16)(u >> 16);
}

__device__ __forceinline__ void gl_lds16(const void* gsrc, void* ldst) {
  __builtin_amdgcn_global_load_lds(
      (const __attribute__((address_space(1))) unsigned int*)gsrc,
      (__attribute__((address_space(3))) unsigned int*)ldst,
      16, 0, 0);
}

#define MFMA16(a, b, c) __builtin_amdgcn_mfma_f32_16x16x32_bf16((a), (b), (c), 0, 0, 0)
#define VMW(N) asm volatile("s_waitcnt vmcnt(" #N ")" ::: "memory")
#define BARM() asm volatile("s_barrier" ::: "memory")

// ---------------- fused prep: fp32->bf16 convert + RoPE table + mask flags ----------------
// blocks [0,2048): grid-stride convert of x + 4 weights (2M float4, 4 iters)
// blocks [2048,2304): RoPE cos/sin table (65536 entries)
// blocks [2304,2368): per-(b, kv-tile-of-64) all-valid flags
__global__ __launch_bounds__(256) void prep_all(
    const float* x, const float* wq, const float* wk, const float* wv, const float* wo,
    const int* amask,
    u16* xb, u16* wqb, u16* wkb, u16* wvb, u16* wob, float2* tab, int* mflag)
{
  const int bid = blockIdx.x;
  if (bid < 2048) {
#pragma unroll
    for (int it = 0; it < 4; ++it) {
      size_t i = ((size_t)bid * 256 + threadIdx.x) * 4 + (size_t)it * 2097152u;
      const float* src; u16* dst; size_t off;
      if (i < 4194304u)      { src = x;  dst = xb;  off = i; }
      else if (i < 5242880u) { src = wq; dst = wqb; off = i - 4194304u; }
      else if (i < 6291456u) { src = wk; dst = wkb; off = i - 5242880u; }
      else if (i < 7340032u) { src = wv; dst = wvb; off = i - 6291456u; }
      else                   { src = wo; dst = wob; off = i - 7340032u; }
      float4 v = *(const float4*)(src + off);
      ushort4 o;
      o.x = f2bf(v.x); o.y = f2bf(v.y); o.z = f2bf(v.z); o.w = f2bf(v.w);
      *(ushort4*)(dst + off) = o;
    }
  } else if (bid < 2304) {
    int i = (bid - 2048) * 256 + threadIdx.x;
    int pos = i >> 5, f = i & 31;
    float inv = powf(10000.0f, -(float)f / 32.0f);
    float ang = (float)pos * inv;
    tab[i] = make_float2(cosf(ang), sinf(ang));
  } else {
    const int f = bid - 2304;           // 0..63: b = f>>5, tile = f&31
    if (threadIdx.x < 64) {             // wave 0 only
      const int b = f >> 5, t = f & 31;
      int v = amask[b * S_LEN + t * 64 + threadIdx.x];
      int all = (int)__all(v != 0);
      if (threadIdx.x == 0) mflag[f] = all;
    }
  }
}

// ================= QKV projection: 128x128 tiles, counted-vmcnt dbuf (R6-best) =================
// Grid 768 = 8 XCD x (4 m-panels x 24 n-cols). VMW(8) drains the previous stage
// exactly one iteration after issue; raw s_barrier (no vmcnt0 drain).
// Q epilogue folds 1/sqrt(DK) * log2(e) so attention softmax can use exp2 directly.
__global__ __launch_bounds__(256) void gemm_qkv128(
    const u16* xb, const u16* wqb, const u16* wkb, const u16* wvb,
    const float2* tab, u16* Qr, u16* Kr, u16* Vt)
{
  __shared__ __align__(16) u16 ldsA[2][128 * 64];
  __shared__ __align__(16) u16 ldsB[2][128 * 64];

  const int bid = blockIdx.x;
  const int xcd = bid & 7, v = bid >> 3;        // v 0..95
  const int m0 = (xcd * 4 + (v & 3)) * 128;     // 4 m-panels per XCD
  const int nc = v >> 2;                        // 0..23
  const int z = nc >> 3;                        // 0=Q 1=K 2=V
  const int n0z = (nc & 7) * 128;
  const u16* Wz = (z == 0) ? wqb : ((z == 1) ? wkb : wvb);

  const int tid = threadIdx.x;
  const int w = tid >> 6, lane = tid & 63;
  const int l15 = lane & 15, g = lane >> 4;
  const int wm = (w >> 1) * 64, wn = (w & 1) * 64;
  const int lrow = lane >> 3;
  const int scolb = ((lane & 7) * 16) ^ (lrow << 4);
  f32x4 acc[4][4] = {};

  auto stage = [&](int buf, int kt) {
#pragma unroll
    for (int c = 0; c < 4; ++c) {
      const int rb = w * 32 + c * 8;
      const int row = rb + lrow;
      gl_lds16((const char*)(xb + (size_t)(m0 + row) * DM + kt) + scolb,
               (char*)&ldsA[buf][0] + rb * 128);
      gl_lds16((const char*)(Wz + (size_t)(n0z + row) * DM + kt) + scolb,
               (char*)&ldsB[buf][0] + rb * 128);
    }
  };

  stage(0, 0);                     // 8 outstanding
  int cur = 0;
  for (int kt = 0; kt < DM; kt += 64) {
    if (kt + 64 < DM) { stage(cur ^ 1, kt + 64); VMW(8); } else { VMW(0); }
    BARM();
#pragma unroll
    for (int ks = 0; ks < 2; ++ks) {
      bf16x8 af[4], bfr[4];
#pragma unroll
      for (int i = 0; i < 4; ++i) {
        const int ar = wm + i * 16 + l15;
        af[i] = *(const bf16x8*)((const char*)&ldsA[cur][0] + ar * 128 +
                                 ((ks * 64 + g * 16) ^ ((ar & 7) << 4)));
        const int br = wn + i * 16 + l15;
        bfr[i] = *(const bf16x8*)((const char*)&ldsB[cur][0] + br * 128 +
                                  ((ks * 64 + g * 16) ^ ((br & 7) << 4)));
      }
      __builtin_amdgcn_s_setprio(1);
#pragma unroll
      for (int i = 0; i < 4; ++i)
#pragma unroll
        for (int j = 0; j < 4; ++j)
          acc[i][j] = MFMA16(af[i], bfr[j], acc[i][j]);
      __builtin_amdgcn_s_setprio(0);
    }
    BARM();
    cur ^= 1;
  }

  // epilogue: RoPE (z<2) / V-transpose (z==2)
  u16* dst = (z == 0) ? Qr : Kr;
#pragma unroll
  for (int i = 0; i < 4; ++i) {
#pragma unroll
    for (int j = 0; j < 4; ++j) {
      const int n = n0z + wn + j * 16 + l15;
      const int h = n >> 6, d = n & 63;
#pragma unroll
      for (int r = 0; r < 4; ++r) {
        const int m = m0 + wm + i * 16 + g * 4 + r;
        const int b = m >> 11, s = m & 2047;
        float vv = acc[i][j][r];
        if (z < 2) {
          float p = __shfl_xor(vv, 1);
          float2 cs = tab[s * 32 + (d >> 1)];
          float o = vv * cs.x + ((d & 1) ? p : -p) * cs.y;
          if (z == 0) o *= 0.18033688011f;    // (1/sqrt(64)) * log2(e)
          dst[((size_t)(b * NH + h) * S_LEN + s) * DK + d] = f2bf(o);
        } else {
          Vt[((size_t)(b * NH + h) * DK + d) * S_LEN + s] = f2bf(vv);
        }
      }
    }
  }
}

// ---------------- output GEMM: counted-vmcnt double-buffered 128x128 ----------------
__device__ __forceinline__ void xcd_map(int bid, int& m0, int& n0) {
  const int xcd = bid & 7, v = bid >> 3;
  m0 = (xcd * 4 + (v >> 3)) * 128;
  n0 = (v & 7) * 128;
}

__global__ __launch_bounds__(256) void gemm_out(const u16* ctx, const u16* wob, float* out) {
  __shared__ __align__(16) u16 ldsA[2][128 * 64];
  __shared__ __align__(16) u16 ldsB[2][128 * 64];
  int m0, n0;
  xcd_map(blockIdx.x, m0, n0);

  const int tid = threadIdx.x;
  const int w = tid >> 6, lane = tid & 63;
  const int l15 = lane & 15, g = lane >> 4;
  const int wm = (w >> 1) * 64, wn = (w & 1) * 64;
  const int lrow = lane >> 3;
  const int scolb = ((lane & 7) * 16) ^ (lrow << 4);
  f32x4 acc[4][4] = {};

  auto stage = [&](int buf, int kt) {
#pragma unroll
    for (int c = 0; c < 4; ++c) {
      const int rb = w * 32 + c * 8;
      const int row = rb + lrow;
      gl_lds16((const char*)(ctx + (size_t)(m0 + row) * DM + kt) + scolb,
               (char*)&ldsA[buf][0] + rb * 128);
      gl_lds16((const char*)(wob + (size_t)(n0 + row) * DM + kt) + scolb,
               (char*)&ldsB[buf][0] + rb * 128);
    }
  };

  stage(0, 0);
  int cur = 0;
  for (int kt = 0; kt < DM; kt += 64) {
    if (kt + 64 < DM) { stage(cur ^ 1, kt + 64); VMW(8); } else { VMW(0); }
    BARM();
#pragma unroll
    for (int ks = 0; ks < 2; ++ks) {
      bf16x8 af[4], bfr[4];
#pragma unroll
      for (int i = 0; i < 4; ++i) {
        const int ar = wm + i * 16 + l15;
        af[i] = *(const bf16x8*)((const char*)&ldsA[cur][0] + ar * 128 +
                                 ((ks * 64 + g * 16) ^ ((ar & 7) << 4)));
        const int br = wn + i * 16 + l15;
        bfr[i] = *(const bf16x8*)((const char*)&ldsB[cur][0] + br * 128 +
                                  ((ks * 64 + g * 16) ^ ((br & 7) << 4)));
      }
      __builtin_amdgcn_s_setprio(1);
#pragma unroll
      for (int i = 0; i < 4; ++i)
#pragma unroll
        for (int j = 0; j < 4; ++j)
          acc[i][j] = MFMA16(af[i], bfr[j], acc[i][j]);
      __builtin_amdgcn_s_setprio(0);
    }
    BARM();
    cur ^= 1;
  }

#pragma unroll
  for (int i = 0; i < 4; ++i)
#pragma unroll
    for (int j = 0; j < 4; ++j)
#pragma unroll
      for (int r = 0; r < 4; ++r)
        out[(size_t)(m0 + wm + i * 16 + g * 4 + r) * DM + n0 + wn + j * 16 + l15] = acc[i][j][r];
}

// ---------------- causal flash attention: 8 waves x 16 q-rows, CU-balanced bands ----------------
// Scores arrive pre-scaled by log2(e)/sqrt(DK)  ->  softmax via exp2 (single v_exp_f32).
// band = (by<8) ? 15-by : by-8 : linear blocks c, c+256 (same CU) sum to 15 -> 36 iters/CU.
__global__ __launch_bounds__(512, 4) void attn11(
    const u16* Qr, const u16* Kr, const u16* Vt, const int* amask, const int* mflag,
    u16* ctx)
{
  __shared__ __align__(16) u16 ldsK[2][64 * 64];
  __shared__ __align__(16) u16 ldsV[2][64 * 64];
  __shared__ __align__(16) __bf16 plds[8][16 * 72];

  const int bh = blockIdx.x;
  const int by = blockIdx.y;
  const int band = (by < 8) ? (15 - by) : (by - 8);
  const int b = bh >> 4, h = bh & 15;
  const int tid = threadIdx.x, w8 = tid >> 6, lane = tid & 63;
  const int l15 = lane & 15, g = lane >> 4;
  const int r8 = lane >> 3;
  const int sw = ((lane & 7) * 16) ^ (r8 << 4);

  const int chunk = band * 4 + (w8 >> 1);          // 32-row chunk, 0..63
  const int q0 = chunk * 32 + (w8 & 1) * 16;
  const int myNt = (chunk >> 1) + 1;
  const int dTile = chunk >> 1;
  const int ntB = band * 2 + 2;

  const u16* Kb0 = Kr + (size_t)bh * S_LEN * DK;
  const u16* Vb0 = Vt + (size_t)bh * DK * S_LEN;
  const u16* Qb  = Qr + (size_t)bh * S_LEN * DK;

  bf16x8 qa0 = *(const bf16x8*)(Qb + (size_t)(q0 + l15) * DK + g * 8);
  bf16x8 qa1 = *(const bf16x8*)(Qb + (size_t)(q0 + l15) * DK + 32 + g * 8);

  union { u16 u[8]; bf16x8 v; } one_u;
#pragma unroll
  for (int i = 0; i < 8; ++i) one_u.u[i] = 0x3F80;
  const bf16x8 ones = one_u.v;

  float m[4];
  f32x4 lacc = {0.f, 0.f, 0.f, 0.f};
  f32x4 o[4];
#pragma unroll
  for (int r = 0; r < 4; ++r) m[r] = -3e38f;
#pragma unroll
  for (int dt = 0; dt < 4; ++dt) o[dt] = (f32x4){0.f, 0.f, 0.f, 0.f};

  auto stage = [&](int buf, int t) {
    const size_t kv0 = (size_t)t * 64;
    const int row = w8 * 8 + r8;
    gl_lds16((const char*)(Kb0 + (kv0 + row) * DK) + sw,
             (char*)&ldsK[buf][0] + (w8 * 8) * 128);
    gl_lds16((const char*)(Vb0 + (size_t)row * S_LEN + kv0) + sw,
             (char*)&ldsV[buf][0] + (w8 * 8) * 128);
  };

  stage(0, 0);
  int cur = 0;

  for (int t = 0; t < ntB; ++t) {
    if (t + 1 < ntB) { stage(cur ^ 1, t + 1); VMW(2); } else { VMW(0); }
    BARM();
    if (t < myNt) {
      const int kv0 = t * 64;
      const bool allok = mflag[(b << 5) + t] != 0;

      bf16x8 kb[4][2];
#pragma unroll
      for (int nt = 0; nt < 4; ++nt) {
        const int row = nt * 16 + l15;
#pragma unroll
        for (int ks = 0; ks < 2; ++ks)
          kb[nt][ks] = *(const bf16x8*)((const char*)&ldsK[cur][0] + row * 128 +
                                        ((ks * 64 + g * 16) ^ ((row & 7) << 4)));
      }
      f32x4 s[4];
#pragma unroll
      for (int nt = 0; nt < 4; ++nt) s[nt] = (f32x4){0.f, 0.f, 0.f, 0.f};
      __builtin_amdgcn_s_setprio(1);
#pragma unroll
      for (int nt = 0; nt < 4; ++nt) {
        s[nt] = MFMA16(qa0, kb[nt][0], s[nt]);
        s[nt] = MFMA16(qa1, kb[nt][1], s[nt]);
      }
      __builtin_amdgcn_s_setprio(0);

      if (!allok) {
#pragma unroll
        for (int nt = 0; nt < 4; ++nt) {
          const int pmv = amask[b * S_LEN + kv0 + nt * 16 + l15];
#pragma unroll
          for (int r = 0; r < 4; ++r)
            if (!pmv) s[nt][r] = -1e9f;
        }
      }
      if (t == dTile) {
#pragma unroll
        for (int nt = 0; nt < 4; ++nt) {
          const int kvc = kv0 + nt * 16 + l15;
#pragma unroll
          for (int r = 0; r < 4; ++r)
            s[nt][r] = (kvc <= q0 + g * 4 + r) ? s[nt][r] : -1e9f;
        }
      }

      float tmax[4];
      bool need = false;
#pragma unroll
      for (int r = 0; r < 4; ++r) {
        float t0 = fmaxf(fmaxf(s[0][r], s[1][r]), fmaxf(s[2][r], s[3][r]));
        t0 = fmaxf(t0, __shfl_xor(t0, 1));
        t0 = fmaxf(t0, __shfl_xor(t0, 2));
        t0 = fmaxf(t0, __shfl_xor(t0, 4));
        t0 = fmaxf(t0, __shfl_xor(t0, 8));
        tmax[r] = t0;
        need = need || (t0 > m[r] + 11.5415603f);   // 8 * log2(e)
      }
      if (__any((int)need)) {                // T13: rescale only on growth
#pragma unroll
        for (int r = 0; r < 4; ++r) {
          const float mnew = fmaxf(m[r], tmax[r]);
          const float alpha = exp2f(m[r] - mnew);
          m[r] = mnew;
          lacc[r] *= alpha;
#pragma unroll
          for (int dt = 0; dt < 4; ++dt) o[dt][r] *= alpha;
        }
      }
      __bf16* pw = &plds[w8][0];
#pragma unroll
      for (int r = 0; r < 4; ++r) {
#pragma unroll
        for (int nt = 0; nt < 4; ++nt)
          pw[(g * 4 + r) * 72 + nt * 16 + l15] = (__bf16)exp2f(s[nt][r] - m[r]);
      }
      bf16x8 pa0 = *(const bf16x8*)(pw + l15 * 72 + g * 8);
      bf16x8 pa1 = *(const bf16x8*)(pw + l15 * 72 + 32 + g * 8);
      bf16x8 vb[4][2];
#pragma unroll
      for (int dt = 0; dt < 4; ++dt) {
        const int row = dt * 16 + l15;
#pragma unroll
        for (int ks = 0; ks < 2; ++ks)
          vb[dt][ks] = *(const bf16x8*)((const char*)&ldsV[cur][0] + row * 128 +
                                        ((ks * 64 + g * 16) ^ ((row & 7) << 4)));
      }
      __builtin_amdgcn_s_setprio(1);
      lacc = MFMA16(pa0, ones, lacc);
      lacc = MFMA16(pa1, ones, lacc);
#pragma unroll
      for (int dt = 0; dt < 4; ++dt) {
        o[dt] = MFMA16(pa0, vb[dt][0], o[dt]);
        o[dt] = MFMA16(pa1, vb[dt][1], o[dt]);
      }
      __builtin_amdgcn_s_setprio(0);
    }
    BARM();
    cur ^= 1;
  }

#pragma unroll
  for (int dt = 0; dt < 4; ++dt)
#pragma unroll
    for (int r = 0; r < 4; ++r) {
      const int q = q0 + g * 4 + r;
      ctx[((size_t)(b * S_LEN + q)) * DM + h * DK + dt * 16 + l15] =
          f2bf(o[dt][r] / lacc[r]);
    }
}

extern "C" void kernel_launch(void* const* d_in, const int* in_sizes, int n_in,
                              void* d_out, int out_size, void* d_ws, size_t ws_size,
                              hipStream_t stream) {
  const float* x   = (const float*)d_in[0];
  const int* amask = (const int*)d_in[1];
  const float* wq  = (const float*)d_in[2];
  const float* wk  = (const float*)d_in[3];
  const float* wv  = (const float*)d_in[4];
  const float* wo  = (const float*)d_in[5];
  float* out = (float*)d_out;

  char* ws = (char*)d_ws;
  u16* xb    = (u16*)(ws);                      // 8 MB
  u16* wqb   = (u16*)(ws + ( 8u << 20));        // 2 MB
  u16* wkb   = (u16*)(ws + (10u << 20));
  u16* wvb   = (u16*)(ws + (12u << 20));
  u16* wob   = (u16*)(ws + (14u << 20));
  float2* tab = (float2*)(ws + (16u << 20));    // 512 KB
  int* mflag = (int*)(ws + (16u << 20) + (768u << 10));   // 256 B
  u16* Qr    = (u16*)(ws + (17u << 20));        // 8 MB  [B,H,S,D]
  u16* Kr    = (u16*)(ws + (25u << 20));        // 8 MB  [B,H,S,D]
  u16* Vt    = (u16*)(ws + (33u << 20));        // 8 MB  [B,H,D,S]
  u16* ctx   = (u16*)(ws + (41u << 20));        // 8 MB  [B,S,H*D]

  hipLaunchKernelGGL(prep_all, dim3(2368), dim3(256), 0, stream,
                     x, wq, wk, wv, wo, amask, xb, wqb, wkb, wvb, wob, tab, mflag);
  hipLaunchKernelGGL(gemm_qkv128, dim3(768), dim3(256), 0, stream,
                     xb, wqb, wkb, wvb, tab, Qr, Kr, Vt);
  hipLaunchKernelGGL(attn11, dim3(32, 16), dim3(512), 0, stream,
                     Qr, Kr, Vt, amask, mflag, ctx);
  hipLaunchKernelGGL(gemm_out, dim3(256), dim3(256), 0, stream, ctx, wob, out);
}

// Round 12
// 144.245 us; speedup vs baseline: 1.0933x; 1.0639x over previous
//
#include <hip/hip_runtime.h>
#include <hip/hip_bf16.h>
#include <cstdint>

typedef unsigned short u16;
typedef __bf16 bf16x8 __attribute__((ext_vector_type(8)));
typedef float f32x4 __attribute__((ext_vector_type(4)));

#define S_LEN 2048
#define NH 16
#define DK 64
#define DM 1024

__device__ __forceinline__ u16 f2bf(float f) {
  union { float f; uint32_t u; } c; c.f = f;
  uint32_t u = c.u;
  u += 0x7fffu + ((u >> 16) & 1u);   // RNE
  return (u16)(u >> 16);
}

__device__ __forceinline__ void gl_lds16(const void* gsrc, void* ldst) {
  __builtin_amdgcn_global_load_lds(
      (const __attribute__((address_space(1))) unsigned int*)gsrc,
      (__attribute__((address_space(3))) unsigned int*)ldst,
      16, 0, 0);
}

#define MFMA16(a, b, c) __builtin_amdgcn_mfma_f32_16x16x32_bf16((a), (b), (c), 0, 0, 0)
#define VMW(N) asm volatile("s_waitcnt vmcnt(" #N ")" ::: "memory")
#define BARM() asm volatile("s_barrier" ::: "memory")

// ---------------- fused prep: fp32->bf16 convert + RoPE table + mask flags ----------------
__global__ __launch_bounds__(256) void prep_all(
    const float* x, const float* wq, const float* wk, const float* wv, const float* wo,
    const int* amask,
    u16* xb, u16* wqb, u16* wkb, u16* wvb, u16* wob, float2* tab, int* mflag)
{
  const int bid = blockIdx.x;
  if (bid < 2048) {
#pragma unroll
    for (int it = 0; it < 4; ++it) {
      size_t i = ((size_t)bid * 256 + threadIdx.x) * 4 + (size_t)it * 2097152u;
      const float* src; u16* dst; size_t off;
      if (i < 4194304u)      { src = x;  dst = xb;  off = i; }
      else if (i < 5242880u) { src = wq; dst = wqb; off = i - 4194304u; }
      else if (i < 6291456u) { src = wk; dst = wkb; off = i - 5242880u; }
      else if (i < 7340032u) { src = wv; dst = wvb; off = i - 6291456u; }
      else                   { src = wo; dst = wob; off = i - 7340032u; }
      float4 v = *(const float4*)(src + off);
      ushort4 o;
      o.x = f2bf(v.x); o.y = f2bf(v.y); o.z = f2bf(v.z); o.w = f2bf(v.w);
      *(ushort4*)(dst + off) = o;
    }
  } else if (bid < 2304) {
    int i = (bid - 2048) * 256 + threadIdx.x;
    int pos = i >> 5, f = i & 31;
    float inv = powf(10000.0f, -(float)f / 32.0f);
    float ang = (float)pos * inv;
    tab[i] = make_float2(cosf(ang), sinf(ang));
  } else {
    const int f = bid - 2304;           // 0..63: b = f>>5, tile = f&31
    if (threadIdx.x < 64) {
      const int b = f >> 5, t = f & 31;
      int v = amask[b * S_LEN + t * 64 + threadIdx.x];
      int all = (int)__all(v != 0);
      if (threadIdx.x == 0) mflag[f] = all;
    }
  }
}

// ================= QKV projection: 128x128 tile, BK=32, 4 blocks/CU =================
// LDS 32 KB (2buf x (A[128][32]+B[128][32])) -> 4 blocks x 4 waves = 16 waves/CU;
// wave-level TLP (m114) hides the 1-deep prefetch stall. VMW(4) per K-step.
// LDS rows are 64B: swizzle ((row&3)<<4) spreads 4 slots (4-way read conflict accepted).
__global__ __launch_bounds__(256, 4) void gemm_qkv32(
    const u16* xb, const u16* wqb, const u16* wkb, const u16* wvb,
    const float2* tab, u16* Qr, u16* Kr, u16* Vt)
{
  __shared__ __align__(16) u16 ldsA[2][128 * 32];
  __shared__ __align__(16) u16 ldsB[2][128 * 32];

  const int bid = blockIdx.x;
  const int xcd = bid & 7, v = bid >> 3;        // v 0..95
  const int m0 = (xcd * 4 + (v & 3)) * 128;     // 4 m-panels per XCD (32 total)
  const int nc = v >> 2;                        // 0..23
  const int z = nc >> 3;                        // 0=Q 1=K 2=V
  const int n0z = (nc & 7) * 128;
  const u16* Wz = (z == 0) ? wqb : ((z == 1) ? wkb : wvb);

  const int tid = threadIdx.x;
  const int w = tid >> 6, lane = tid & 63;
  const int l15 = lane & 15, g = lane >> 4;
  const int wm = (w >> 1) * 64, wn = (w & 1) * 64;
  const int lr4 = lane >> 2;                              // 0..15 row in 16-row chunk
  const int scolb = ((lane & 3) * 16) ^ ((lr4 & 3) << 4); // pre-swizzled src byte (64B rows)

  f32x4 acc[4][4] = {};

  auto stage = [&](int buf, int kt) {
#pragma unroll
    for (int c = 0; c < 2; ++c) {
      const int rb = c * 64 + w * 16;
      const int row = rb + lr4;
      gl_lds16((const char*)(xb + (size_t)(m0 + row) * DM + kt) + scolb,
               (char*)&ldsA[buf][0] + rb * 64);
      gl_lds16((const char*)(Wz + (size_t)(n0z + row) * DM + kt) + scolb,
               (char*)&ldsB[buf][0] + rb * 64);
    }
  };

  stage(0, 0);                     // 4 outstanding
  int cur = 0;
  for (int kt = 0; kt < DM; kt += 32) {
    if (kt + 32 < DM) { stage(cur ^ 1, kt + 32); VMW(4); } else { VMW(0); }
    BARM();
    bf16x8 af[4], bfr[4];
#pragma unroll
    for (int i = 0; i < 4; ++i) {
      const int ar = wm + i * 16 + l15;
      af[i] = *(const bf16x8*)((const char*)&ldsA[cur][0] + ar * 64 +
                               ((g * 16) ^ ((ar & 3) << 4)));
      const int br = wn + i * 16 + l15;
      bfr[i] = *(const bf16x8*)((const char*)&ldsB[cur][0] + br * 64 +
                                ((g * 16) ^ ((br & 3) << 4)));
    }
    __builtin_amdgcn_s_setprio(1);
#pragma unroll
    for (int i = 0; i < 4; ++i)
#pragma unroll
      for (int j = 0; j < 4; ++j)
        acc[i][j] = MFMA16(af[i], bfr[j], acc[i][j]);
    __builtin_amdgcn_s_setprio(0);
    BARM();
    cur ^= 1;
  }

  // epilogue: RoPE (z<2, Q scaled by log2e/8) / V-transpose (z==2)
  u16* dst = (z == 0) ? Qr : Kr;
#pragma unroll
  for (int i = 0; i < 4; ++i) {
#pragma unroll
    for (int j = 0; j < 4; ++j) {
      const int n = n0z + wn + j * 16 + l15;
      const int h = n >> 6, d = n & 63;
#pragma unroll
      for (int r = 0; r < 4; ++r) {
        const int m = m0 + wm + i * 16 + g * 4 + r;
        const int b = m >> 11, s = m & 2047;
        float vv = acc[i][j][r];
        if (z < 2) {
          float p = __shfl_xor(vv, 1);
          float2 cs = tab[s * 32 + (d >> 1)];
          float o = vv * cs.x + ((d & 1) ? p : -p) * cs.y;
          if (z == 0) o *= 0.18033688011f;    // (1/sqrt(64)) * log2(e)
          dst[((size_t)(b * NH + h) * S_LEN + s) * DK + d] = f2bf(o);
        } else {
          Vt[((size_t)(b * NH + h) * DK + d) * S_LEN + s] = f2bf(vv);
        }
      }
    }
  }
}

// ================= output GEMM: 128x64 tile, BK=32 =================
// Grid 512 = 8 XCD x (4 m-panels x 16 n-cols): m0 <= 3968+128 = 4096, n0 <= 960+64 = 1024.
__global__ __launch_bounds__(256, 4) void gemm_out64(const u16* ctx, const u16* wob, float* out) {
  __shared__ __align__(16) u16 ldsA[2][128 * 32];
  __shared__ __align__(16) u16 ldsB[2][64 * 32];

  const int bid = blockIdx.x;
  const int xcd = bid & 7, v = bid >> 3;        // v 0..63
  const int m0 = (xcd * 4 + (v & 3)) * 128;     // 32 m-panels
  const int n0 = (v >> 2) * 64;                 // 16 n-cols

  const int tid = threadIdx.x;
  const int w = tid >> 6, lane = tid & 63;
  const int l15 = lane & 15, g = lane >> 4;
  const int wm = (w >> 1) * 64, wn = (w & 1) * 32;
  const int lr4 = lane >> 2;
  const int scolb = ((lane & 3) * 16) ^ ((lr4 & 3) << 4);

  f32x4 acc[4][2] = {};

  auto stage = [&](int buf, int kt) {
#pragma unroll
    for (int c = 0; c < 2; ++c) {
      const int rb = c * 64 + w * 16;
      const int row = rb + lr4;
      gl_lds16((const char*)(ctx + (size_t)(m0 + row) * DM + kt) + scolb,
               (char*)&ldsA[buf][0] + rb * 64);
    }
    const int rb = w * 16;
    const int row = rb + lr4;
    gl_lds16((const char*)(wob + (size_t)(n0 + row) * DM + kt) + scolb,
             (char*)&ldsB[buf][0] + rb * 64);
  };

  stage(0, 0);                     // 3 outstanding
  int cur = 0;
  for (int kt = 0; kt < DM; kt += 32) {
    if (kt + 32 < DM) { stage(cur ^ 1, kt + 32); VMW(3); } else { VMW(0); }
    BARM();
    bf16x8 af[4], bfr[2];
#pragma unroll
    for (int i = 0; i < 4; ++i) {
      const int ar = wm + i * 16 + l15;
      af[i] = *(const bf16x8*)((const char*)&ldsA[cur][0] + ar * 64 +
                               ((g * 16) ^ ((ar & 3) << 4)));
    }
#pragma unroll
    for (int j = 0; j < 2; ++j) {
      const int br = wn + j * 16 + l15;
      bfr[j] = *(const bf16x8*)((const char*)&ldsB[cur][0] + br * 64 +
                                ((g * 16) ^ ((br & 3) << 4)));
    }
    __builtin_amdgcn_s_setprio(1);
#pragma unroll
    for (int i = 0; i < 4; ++i)
#pragma unroll
      for (int j = 0; j < 2; ++j)
        acc[i][j] = MFMA16(af[i], bfr[j], acc[i][j]);
    __builtin_amdgcn_s_setprio(0);
    BARM();
    cur ^= 1;
  }

#pragma unroll
  for (int i = 0; i < 4; ++i)
#pragma unroll
    for (int j = 0; j < 2; ++j)
#pragma unroll
      for (int r = 0; r < 4; ++r)
        out[(size_t)(m0 + wm + i * 16 + g * 4 + r) * DM + n0 + wn + j * 16 + l15] = acc[i][j][r];
}

// ---------------- causal flash attention: 8 waves x 16 q-rows, CU-balanced bands ----------------
// Scores arrive pre-scaled by log2(e)/sqrt(DK)  ->  softmax via exp2 (single v_exp_f32).
__global__ __launch_bounds__(512, 4) void attn11(
    const u16* Qr, const u16* Kr, const u16* Vt, const int* amask, const int* mflag,
    u16* ctx)
{
  __shared__ __align__(16) u16 ldsK[2][64 * 64];
  __shared__ __align__(16) u16 ldsV[2][64 * 64];
  __shared__ __align__(16) __bf16 plds[8][16 * 72];

  const int bh = blockIdx.x;
  const int by = blockIdx.y;
  const int band = (by < 8) ? (15 - by) : (by - 8);
  const int b = bh >> 4, h = bh & 15;
  const int tid = threadIdx.x, w8 = tid >> 6, lane = tid & 63;
  const int l15 = lane & 15, g = lane >> 4;
  const int r8 = lane >> 3;
  const int sw = ((lane & 7) * 16) ^ (r8 << 4);

  const int chunk = band * 4 + (w8 >> 1);          // 32-row chunk, 0..63
  const int q0 = chunk * 32 + (w8 & 1) * 16;
  const int myNt = (chunk >> 1) + 1;
  const int dTile = chunk >> 1;
  const int ntB = band * 2 + 2;

  const u16* Kb0 = Kr + (size_t)bh * S_LEN * DK;
  const u16* Vb0 = Vt + (size_t)bh * DK * S_LEN;
  const u16* Qb  = Qr + (size_t)bh * S_LEN * DK;

  bf16x8 qa0 = *(const bf16x8*)(Qb + (size_t)(q0 + l15) * DK + g * 8);
  bf16x8 qa1 = *(const bf16x8*)(Qb + (size_t)(q0 + l15) * DK + 32 + g * 8);

  union { u16 u[8]; bf16x8 v; } one_u;
#pragma unroll
  for (int i = 0; i < 8; ++i) one_u.u[i] = 0x3F80;
  const bf16x8 ones = one_u.v;

  float m[4];
  f32x4 lacc = {0.f, 0.f, 0.f, 0.f};
  f32x4 o[4];
#pragma unroll
  for (int r = 0; r < 4; ++r) m[r] = -3e38f;
#pragma unroll
  for (int dt = 0; dt < 4; ++dt) o[dt] = (f32x4){0.f, 0.f, 0.f, 0.f};

  auto stage = [&](int buf, int t) {
    const size_t kv0 = (size_t)t * 64;
    const int row = w8 * 8 + r8;
    gl_lds16((const char*)(Kb0 + (kv0 + row) * DK) + sw,
             (char*)&ldsK[buf][0] + (w8 * 8) * 128);
    gl_lds16((const char*)(Vb0 + (size_t)row * S_LEN + kv0) + sw,
             (char*)&ldsV[buf][0] + (w8 * 8) * 128);
  };

  stage(0, 0);
  int cur = 0;

  for (int t = 0; t < ntB; ++t) {
    if (t + 1 < ntB) { stage(cur ^ 1, t + 1); VMW(2); } else { VMW(0); }
    BARM();
    if (t < myNt) {
      const int kv0 = t * 64;
      const bool allok = mflag[(b << 5) + t] != 0;

      bf16x8 kb[4][2];
#pragma unroll
      for (int nt = 0; nt < 4; ++nt) {
        const int row = nt * 16 + l15;
#pragma unroll
        for (int ks = 0; ks < 2; ++ks)
          kb[nt][ks] = *(const bf16x8*)((const char*)&ldsK[cur][0] + row * 128 +
                                        ((ks * 64 + g * 16) ^ ((row & 7) << 4)));
      }
      f32x4 s[4];
#pragma unroll
      for (int nt = 0; nt < 4; ++nt) s[nt] = (f32x4){0.f, 0.f, 0.f, 0.f};
      __builtin_amdgcn_s_setprio(1);
#pragma unroll
      for (int nt = 0; nt < 4; ++nt) {
        s[nt] = MFMA16(qa0, kb[nt][0], s[nt]);
        s[nt] = MFMA16(qa1, kb[nt][1], s[nt]);
      }
      __builtin_amdgcn_s_setprio(0);

      if (!allok) {
#pragma unroll
        for (int nt = 0; nt < 4; ++nt) {
          const int pmv = amask[b * S_LEN + kv0 + nt * 16 + l15];
#pragma unroll
          for (int r = 0; r < 4; ++r)
            if (!pmv) s[nt][r] = -1e9f;
        }
      }
      if (t == dTile) {
#pragma unroll
        for (int nt = 0; nt < 4; ++nt) {
          const int kvc = kv0 + nt * 16 + l15;
#pragma unroll
          for (int r = 0; r < 4; ++r)
            s[nt][r] = (kvc <= q0 + g * 4 + r) ? s[nt][r] : -1e9f;
        }
      }

      float tmax[4];
      bool need = false;
#pragma unroll
      for (int r = 0; r < 4; ++r) {
        float t0 = fmaxf(fmaxf(s[0][r], s[1][r]), fmaxf(s[2][r], s[3][r]));
        t0 = fmaxf(t0, __shfl_xor(t0, 1));
        t0 = fmaxf(t0, __shfl_xor(t0, 2));
        t0 = fmaxf(t0, __shfl_xor(t0, 4));
        t0 = fmaxf(t0, __shfl_xor(t0, 8));
        tmax[r] = t0;
        need = need || (t0 > m[r] + 11.5415603f);   // 8 * log2(e)
      }
      if (__any((int)need)) {                // T13: rescale only on growth
#pragma unroll
        for (int r = 0; r < 4; ++r) {
          const float mnew = fmaxf(m[r], tmax[r]);
          const float alpha = exp2f(m[r] - mnew);
          m[r] = mnew;
          lacc[r] *= alpha;
#pragma unroll
          for (int dt = 0; dt < 4; ++dt) o[dt][r] *= alpha;
        }
      }
      __bf16* pw = &plds[w8][0];
#pragma unroll
      for (int r = 0; r < 4; ++r) {
#pragma unroll
        for (int nt = 0; nt < 4; ++nt)
          pw[(g * 4 + r) * 72 + nt * 16 + l15] = (__bf16)exp2f(s[nt][r] - m[r]);
      }
      bf16x8 pa0 = *(const bf16x8*)(pw + l15 * 72 + g * 8);
      bf16x8 pa1 = *(const bf16x8*)(pw + l15 * 72 + 32 + g * 8);
      bf16x8 vb[4][2];
#pragma unroll
      for (int dt = 0; dt < 4; ++dt) {
        const int row = dt * 16 + l15;
#pragma unroll
        for (int ks = 0; ks < 2; ++ks)
          vb[dt][ks] = *(const bf16x8*)((const char*)&ldsV[cur][0] + row * 128 +
                                        ((ks * 64 + g * 16) ^ ((row & 7) << 4)));
      }
      __builtin_amdgcn_s_setprio(1);
      lacc = MFMA16(pa0, ones, lacc);
      lacc = MFMA16(pa1, ones, lacc);
#pragma unroll
      for (int dt = 0; dt < 4; ++dt) {
        o[dt] = MFMA16(pa0, vb[dt][0], o[dt]);
        o[dt] = MFMA16(pa1, vb[dt][1], o[dt]);
      }
      __builtin_amdgcn_s_setprio(0);
    }
    BARM();
    cur ^= 1;
  }

#pragma unroll
  for (int dt = 0; dt < 4; ++dt)
#pragma unroll
    for (int r = 0; r < 4; ++r) {
      const int q = q0 + g * 4 + r;
      ctx[((size_t)(b * S_LEN + q)) * DM + h * DK + dt * 16 + l15] =
          f2bf(o[dt][r] / lacc[r]);
    }
}

extern "C" void kernel_launch(void* const* d_in, const int* in_sizes, int n_in,
                              void* d_out, int out_size, void* d_ws, size_t ws_size,
                              hipStream_t stream) {
  const float* x   = (const float*)d_in[0];
  const int* amask = (const int*)d_in[1];
  const float* wq  = (const float*)d_in[2];
  const float* wk  = (const float*)d_in[3];
  const float* wv  = (const float*)d_in[4];
  const float* wo  = (const float*)d_in[5];
  float* out = (float*)d_out;

  char* ws = (char*)d_ws;
  u16* xb    = (u16*)(ws);                      // 8 MB
  u16* wqb   = (u16*)(ws + ( 8u << 20));        // 2 MB
  u16* wkb   = (u16*)(ws + (10u << 20));
  u16* wvb   = (u16*)(ws + (12u << 20));
  u16* wob   = (u16*)(ws + (14u << 20));
  float2* tab = (float2*)(ws + (16u << 20));    // 512 KB
  int* mflag = (int*)(ws + (16u << 20) + (768u << 10));   // 256 B
  u16* Qr    = (u16*)(ws + (17u << 20));        // 8 MB  [B,H,S,D]
  u16* Kr    = (u16*)(ws + (25u << 20));        // 8 MB  [B,H,S,D]
  u16* Vt    = (u16*)(ws + (33u << 20));        // 8 MB  [B,H,D,S]
  u16* ctx   = (u16*)(ws + (41u << 20));        // 8 MB  [B,S,H*D]

  hipLaunchKernelGGL(prep_all, dim3(2368), dim3(256), 0, stream,
                     x, wq, wk, wv, wo, amask, xb, wqb, wkb, wvb, wob, tab, mflag);
  hipLaunchKernelGGL(gemm_qkv32, dim3(768), dim3(256), 0, stream,
                     xb, wqb, wkb, wvb, tab, Qr, Kr, Vt);
  hipLaunchKernelGGL(attn11, dim3(32, 16), dim3(512), 0, stream,
                     Qr, Kr, Vt, amask, mflag, ctx);
  hipLaunchKernelGGL(gemm_out64, dim3(512), dim3(256), 0, stream, ctx, wob, out);
}